// Round 12
// baseline (398.544 us; speedup 1.0000x reference)
//
#include <hip/hip_runtime.h>
#include <stdint.h>

typedef __attribute__((ext_vector_type(8))) short short8;
typedef __attribute__((ext_vector_type(4))) short short4v;
typedef __attribute__((ext_vector_type(4))) float floatx4;
typedef _Float16 half2v __attribute__((ext_vector_type(2)));

__device__ __forceinline__ float b2f(unsigned short u) {
  union { unsigned int i; float f; } v; v.i = ((unsigned int)u) << 16; return v.f;
}
__device__ __forceinline__ unsigned short f2b(float f) {
  union { float f; unsigned int i; } v; v.f = f;
  unsigned int i = v.i;
  return (unsigned short)((i + 0x7FFFu + ((i >> 16) & 1u)) >> 16);
}
__device__ __forceinline__ short4v pack4(float a, float b, float c, float d) {
  short4v r;
  r[0] = (short)f2b(a); r[1] = (short)f2b(b); r[2] = (short)f2b(c); r[3] = (short)f2b(d);
  return r;
}

// global -> LDS 16B per lane. lds_base wave-uniform; HW adds lane*16B.
__device__ __forceinline__ void stage16(const unsigned short* g, unsigned short* lds_base) {
  __builtin_amdgcn_global_load_lds((__attribute__((address_space(1))) const unsigned int*)g,
                                   (__attribute__((address_space(3))) unsigned int*)lds_base,
                                   16, 0, 0);
}

// ---------------------------------------------------------------------------
// r0/r7/r9-verified 128x128 BK=32 GEMM core (device fn; LDS passed in).
// C[m0+..][n0+..] = sum_k A[row][k]*B[col][k]; optional 1/rd row-scale, bias.
// ---------------------------------------------------------------------------
__device__ __forceinline__ void gemm128_core(
    unsigned short* As, unsigned short* Bs,
    const unsigned short* __restrict__ A, const unsigned short* __restrict__ B,
    unsigned short* __restrict__ Cb, float* __restrict__ Cf,
    const float* __restrict__ rd, const float* __restrict__ bias,
    int K, int lda, int ldb, int ldc, int m0, int n0)
{
  const int tid  = threadIdx.x;
  const int lane = tid & 63;
  const int wave = tid >> 6;
  const int wr = wave >> 1, wc = wave & 1;

  floatx4 acc[4][4];
#pragma unroll
  for (int i = 0; i < 4; ++i)
#pragma unroll
    for (int j = 0; j < 4; ++j) acc[i][j] = floatx4{0.f, 0.f, 0.f, 0.f};

  const int t    = (lane & 7) ^ (lane >> 3);
  const int srow = 2 * (lane >> 3) + (t >> 2);
  const int scol = (t & 3) * 8;
  const unsigned short* ga0 = A + (long long)(m0 + wave * 32 + srow) * lda + scol;
  const unsigned short* ga1 = ga0 + 16LL * lda;
  const unsigned short* gb0 = B + (long long)(n0 + wave * 32 + srow) * ldb + scol;
  const unsigned short* gb1 = gb0 + 16LL * ldb;
  unsigned short* lA0 = As + wave * 1024;
  unsigned short* lA1 = lA0 + 512;
  unsigned short* lB0 = Bs + wave * 1024;
  unsigned short* lB1 = lB0 + 512;

  const int l15  = lane & 15;
  const int q    = lane >> 4;
  const int rofs = (l15 >> 1) * 64 + (((q + 4 * (l15 & 1)) ^ (l15 >> 1)) * 8);

  for (int kt = 0; kt < K; kt += 32) {
    __syncthreads();
    stage16(ga0 + kt, lA0);
    stage16(ga1 + kt, lA1);
    stage16(gb0 + kt, lB0);
    stage16(gb1 + kt, lB1);
    __syncthreads();
    short8 af[4], bfv[4];
#pragma unroll
    for (int i = 0; i < 4; ++i) af[i]  = *(const short8*)&As[(wr * 32 + i * 8) * 64 + rofs];
#pragma unroll
    for (int j = 0; j < 4; ++j) bfv[j] = *(const short8*)&Bs[(wc * 32 + j * 8) * 64 + rofs];
#pragma unroll
    for (int i = 0; i < 4; ++i)
#pragma unroll
      for (int j = 0; j < 4; ++j)
        acc[i][j] = __builtin_amdgcn_mfma_f32_16x16x32_bf16(bfv[j], af[i], acc[i][j], 0, 0, 0);
  }

#pragma unroll
  for (int i = 0; i < 4; ++i) {
    const int row = m0 + wr * 64 + i * 16 + l15;
    const float rcp = rd ? __builtin_amdgcn_rcpf(rd[row]) : 1.0f;
#pragma unroll
    for (int j = 0; j < 4; ++j) {
      const int colb = n0 + wc * 64 + j * 16 + q * 4;
      floatx4 v = acc[i][j];
      if (rd) { v[0] *= rcp; v[1] *= rcp; v[2] *= rcp; v[3] *= rcp; }
      if (bias) {
        const float4 bi = *(const float4*)&bias[colb];
        v[0] += bi.x; v[1] += bi.y; v[2] += bi.z; v[3] += bi.w;
      }
      if (Cb) *(short4v*)&Cb[(long long)row * ldc + colb] = pack4(v[0], v[1], v[2], v[3]);
      else    *(floatx4*)&Cf[(long long)row * ldc + colb] = v;
    }
  }
}

// ---------------------------------------------------------------------------
// fused_mid: qk GEMM (x=0..95 per z) || vpT GEMM (x=96..143 per z).
// Independent outputs; vpT's 768 blocks fill qk's scheduling tail.
// ---------------------------------------------------------------------------
__global__ __launch_bounds__(256, 4) void fused_mid(
    const unsigned short* __restrict__ xb, const unsigned short* __restrict__ WqkvT,
    const unsigned short* __restrict__ Wcomb,
    unsigned short* __restrict__ qk, unsigned short* __restrict__ vpT,
    const float* __restrict__ b_qkv)
{
  __shared__ unsigned short As[128 * 32];
  __shared__ unsigned short Bs[128 * 32];
  const int x  = blockIdx.x;
  const int bz = blockIdx.z;
  if (x < 96) {
    // qk = x @ Wqkv[:, :1536] + b_qkv : m0 encodes batch rows (bz*1024)
    const int m0 = (bz * 8 + (x & 7)) * 128;
    const int n0 = (x >> 3) * 128;
    gemm128_core(As, Bs, xb, WqkvT, qk, (float*)0, (const float*)0, b_qkv,
                 768, 768, 768, 1536, m0, n0);
  } else {
    // vpT[b][j][m] = sum_k Wcomb[j][k] * x[b][m][k]
    const int a  = x - 96;
    const int m0 = (a >> 3) * 128;          // Wcomb rows (768)
    const int n0 = (a & 7) * 128;           // x rows (1024)
    gemm128_core(As, Bs, Wcomb, xb + (long long)bz * 1024 * 768,
                 vpT + (long long)bz * 768 * 1024, (float*)0,
                 (const float*)0, (const float*)0,
                 768, 768, 768, 1024, m0, n0);
  }
}

// final: out[m][j] = (1/L[m]) * sum_n wmat[m][n] * vpT[j][n] + bias2[j]
__global__ __launch_bounds__(256, 4) void gemm_final(
    const unsigned short* __restrict__ wmat, const unsigned short* __restrict__ vpT,
    float* __restrict__ out, const float* __restrict__ L, const float* __restrict__ bias2)
{
  __shared__ unsigned short As[128 * 32];
  __shared__ unsigned short Bs[128 * 32];
  const int bz = blockIdx.z;
  gemm128_core(As, Bs, wmat + (long long)bz * 1024 * 1024, vpT + (long long)bz * 768 * 1024,
               (unsigned short*)0, out + (long long)bz * 1024 * 768,
               L + bz * 1024, bias2,
               1024, 1024, 1024, 768, blockIdx.y * 128, blockIdx.x * 128);
}

// ---------------------------------------------------------------------------
// Fused scores + group + exp (verified r9: rect XCD swizzle).
// ---------------------------------------------------------------------------
__global__ __launch_bounds__(256) void score_weights(
    const unsigned short* __restrict__ qkv, const unsigned short* __restrict__ gw,
    unsigned short* __restrict__ Wout, float* __restrict__ L,
    const float* __restrict__ alpha)
{
  const int tid  = threadIdx.x;
  const int lane = tid & 63;
  const int wave = tid >> 6;
  const int wr = wave >> 1, wc = wave & 1;
  const int bx = blockIdx.x;             // == xcd
  const int by = blockIdx.y;
  const int m0 = ((bx >> 1) * 2 + (by >> 2)) * 128;
  const int n0 = ((bx & 1) * 4 + (by & 3)) * 128;
  const int b  = blockIdx.z;

  const int l15 = lane & 15;
  const int q   = lane >> 4;
  const int q8  = q * 8;

  const unsigned short* gq = gw + ((long long)(b * 1024 + m0 + wr * 64)) * 64;
  const unsigned short* gk = gw + ((long long)(b * 1024 + n0 + wc * 64)) * 64;
  floatx4 gacc[4][4];
#pragma unroll
  for (int i = 0; i < 4; ++i)
#pragma unroll
    for (int j = 0; j < 4; ++j) gacc[i][j] = floatx4{0.f, 0.f, 0.f, 0.f};
#pragma unroll
  for (int ks = 0; ks < 2; ++ks) {
    short8 af[4], bfv[4];
#pragma unroll
    for (int i = 0; i < 4; ++i) af[i]  = *(const short8*)&gq[(long long)(i * 16 + l15) * 64 + ks * 32 + q8];
#pragma unroll
    for (int j = 0; j < 4; ++j) bfv[j] = *(const short8*)&gk[(long long)(j * 16 + l15) * 64 + ks * 32 + q8];
#pragma unroll
    for (int i = 0; i < 4; ++i)
#pragma unroll
      for (int j = 0; j < 4; ++j)
        gacc[i][j] = __builtin_amdgcn_mfma_f32_16x16x32_bf16(bfv[j], af[i], gacc[i][j], 0, 0, 0);
  }
  const float aa    = 1.0f / (1.0f + __expf(-alpha[0]));
  const float onema = 1.0f - aa;
  half2v gfp[4][4][2];
#pragma unroll
  for (int i = 0; i < 4; ++i)
#pragma unroll
    for (int j = 0; j < 4; ++j) {
      gfp[i][j][0] = half2v{(_Float16)(aa + onema * gacc[i][j][0]),
                            (_Float16)(aa + onema * gacc[i][j][1])};
      gfp[i][j][1] = half2v{(_Float16)(aa + onema * gacc[i][j][2]),
                            (_Float16)(aa + onema * gacc[i][j][3])};
    }

  const unsigned short* Aq = qkv + ((long long)(b * 1024 + m0)) * 1536;        // q cols 0..767
  const unsigned short* Bk = qkv + ((long long)(b * 1024 + n0)) * 1536 + 768;  // k cols 768..1535

  __shared__ unsigned short As[128 * 32];
  __shared__ unsigned short Bs[128 * 32];

  floatx4 sacc[4][4];
#pragma unroll
  for (int i = 0; i < 4; ++i)
#pragma unroll
    for (int j = 0; j < 4; ++j) sacc[i][j] = floatx4{0.f, 0.f, 0.f, 0.f};

  const int t    = (lane & 7) ^ (lane >> 3);
  const int srow = 2 * (lane >> 3) + (t >> 2);
  const int scol = (t & 3) * 8;
  const unsigned short* ga0 = Aq + (long long)(wave * 32 + srow) * 1536 + scol;
  const unsigned short* ga1 = ga0 + 16LL * 1536;
  const unsigned short* gb0 = Bk + (long long)(wave * 32 + srow) * 1536 + scol;
  const unsigned short* gb1 = gb0 + 16LL * 1536;
  unsigned short* lA0 = As + wave * 1024;
  unsigned short* lA1 = lA0 + 512;
  unsigned short* lB0 = Bs + wave * 1024;
  unsigned short* lB1 = lB0 + 512;

  const int rofs = (l15 >> 1) * 64 + (((q + 4 * (l15 & 1)) ^ (l15 >> 1)) * 8);

  for (int kt = 0; kt < 768; kt += 32) {
    __syncthreads();
    stage16(ga0 + kt, lA0);
    stage16(ga1 + kt, lA1);
    stage16(gb0 + kt, lB0);
    stage16(gb1 + kt, lB1);
    __syncthreads();
    short8 af[4], bfv[4];
#pragma unroll
    for (int i = 0; i < 4; ++i) af[i]  = *(const short8*)&As[(wr * 32 + i * 8) * 64 + rofs];
#pragma unroll
    for (int j = 0; j < 4; ++j) bfv[j] = *(const short8*)&Bs[(wc * 32 + j * 8) * 64 + rofs];
#pragma unroll
    for (int i = 0; i < 4; ++i)
#pragma unroll
      for (int j = 0; j < 4; ++j)
        sacc[i][j] = __builtin_amdgcn_mfma_f32_16x16x32_bf16(bfv[j], af[i], sacc[i][j], 0, 0, 0);
  }

  const float scale = 0.03608439182435161f;
  unsigned short* Wb = Wout + ((long long)b << 20);

#pragma unroll
  for (int i = 0; i < 4; ++i) {
    const int row = m0 + wr * 64 + i * 16 + l15;
    float ls = 0.0f;
#pragma unroll
    for (int j = 0; j < 4; ++j) {
      const int colb = n0 + wc * 64 + j * 16 + q * 4;
      float e0 = __expf(sacc[i][j][0] * scale);
      float e1 = __expf(sacc[i][j][1] * scale);
      float e2 = __expf(sacc[i][j][2] * scale);
      float e3 = __expf(sacc[i][j][3] * scale);
      ls += (e0 + e1) + (e2 + e3);
      *(short4v*)&Wb[(long long)row * 1024 + colb] =
        pack4(e0 * (float)gfp[i][j][0][0], e1 * (float)gfp[i][j][0][1],
              e2 * (float)gfp[i][j][1][0], e3 * (float)gfp[i][j][1][1]);
    }
    ls += __shfl_xor(ls, 16, 64);
    ls += __shfl_xor(ls, 32, 64);
    if (lane < 16) atomicAdd(&L[b * 1024 + row], ls);
  }
}

// ---------------------------------------------------------------------------
// MFMA-based gw (verified r5-r9; also zero-inits L).
// ---------------------------------------------------------------------------
__global__ __launch_bounds__(256) void gw_mfma(
    const unsigned short* __restrict__ qkv, const unsigned short* __restrict__ Wgp64,
    unsigned short* __restrict__ gw, float* __restrict__ L)
{
  const int lane = threadIdx.x & 63;
  const int wave = threadIdx.x >> 6;
  const int l15  = lane & 15;
  const int q    = lane >> 4;
  const int q8   = q * 8;
  const long long row0 = (long long)blockIdx.x * 64 + wave * 16;
  const unsigned short* A = qkv + row0 * 1536;

  if (q == 0) L[row0 + l15] = 0.0f;

  floatx4 acc[4];
#pragma unroll
  for (int j = 0; j < 4; ++j) acc[j] = floatx4{0.f, 0.f, 0.f, 0.f};

  for (int kt = 0; kt < 768; kt += 32) {
    short8 af = *(const short8*)&A[(long long)l15 * 1536 + kt + q8];
    short8 bf[4];
#pragma unroll
    for (int j = 0; j < 4; ++j)
      bf[j] = *(const short8*)&Wgp64[(j * 16 + l15) * 768 + kt + q8];
#pragma unroll
    for (int j = 0; j < 4; ++j)
      acc[j] = __builtin_amdgcn_mfma_f32_16x16x32_bf16(bf[j], af, acc[j], 0, 0, 0);
  }

  float mx = -1e30f;
#pragma unroll
  for (int j = 0; j < 4; ++j)
#pragma unroll
    for (int e = 0; e < 4; ++e) {
      const int col = j * 16 + q * 4 + e;
      if (col < 49) mx = fmaxf(mx, acc[j][e]);
    }
  mx = fmaxf(mx, __shfl_xor(mx, 16, 64));
  mx = fmaxf(mx, __shfl_xor(mx, 32, 64));

  float ev[4][4];
  float s = 0.0f;
#pragma unroll
  for (int j = 0; j < 4; ++j)
#pragma unroll
    for (int e = 0; e < 4; ++e) {
      const int col = j * 16 + q * 4 + e;
      const float x = (col < 49) ? __expf(acc[j][e] - mx) : 0.0f;
      ev[j][e] = x;
      s += x;
    }
  s += __shfl_xor(s, 16, 64);
  s += __shfl_xor(s, 32, 64);
  const float inv = 1.0f / s;

  unsigned short* out = gw + (row0 + l15) * 64;
#pragma unroll
  for (int j = 0; j < 4; ++j)
    *(short4v*)&out[j * 16 + q * 4] =
      pack4(ev[j][0] * inv, ev[j][1] * inv, ev[j][2] * inv, ev[j][3] * inv);
}

// ---------------------------------------------------------------------------
// Mega-prep: ONE launch, block-range dispatch. All parts read only kernel
// inputs (no intra-launch dependencies):
//   [0,2048)      convert x -> xb (grid-stride, 16B stores)
//   [2048,3200)   transpose W_qkv[:, :1536] -> WqkvT (48 x 24)
//   [3200,3248)   transpose W_gp -> Wgp64, rows 49..63 zeroed (2 x 24)
//   [3248,3392)   Wcomb[n][k] = sum_d W_proj[d][n]*W_qkv[k][1536+d] (12 x 12)
//                 FIXED r10 bug: B-operand gather was transposed — WvB was a
//                 row-major SLICE (WvB[k][d] = W_qkv[k][1536+d]), not a
//                 transpose; r10 read W_qkv[d][1536+k]. Now contiguous in d
//                 -> 2x float4 per fragment.
//   [3392,3584)   bias2[j] = b_proj[j] + sum_d W_proj[d][j]*b_qkv[1536+d]
// ---------------------------------------------------------------------------
__global__ __launch_bounds__(256) void prep(
    const float* __restrict__ x, const float* __restrict__ W_qkv,
    const float* __restrict__ b_qkv, const float* __restrict__ W_proj,
    const float* __restrict__ b_proj, const float* __restrict__ W_gp,
    unsigned short* __restrict__ xb, unsigned short* __restrict__ WqkvT,
    unsigned short* __restrict__ Wgp64, unsigned short* __restrict__ Wcomb,
    float* __restrict__ bias2)
{
  __shared__ unsigned short tsh[32][33];
  const int blk = blockIdx.x;
  const int tid = threadIdx.x;

  if (blk < 2048) {
    const long long n = 16384LL * 768;
    const long long stride = 2048LL * 256 * 8;
    for (long long i = ((long long)blk * 256 + tid) * 8; i < n; i += stride) {
      const float4 a = *(const float4*)(x + i);
      const float4 b = *(const float4*)(x + i + 4);
      short8 r;
      r[0] = (short)f2b(a.x); r[1] = (short)f2b(a.y); r[2] = (short)f2b(a.z); r[3] = (short)f2b(a.w);
      r[4] = (short)f2b(b.x); r[5] = (short)f2b(b.y); r[6] = (short)f2b(b.z); r[7] = (short)f2b(b.w);
      *(short8*)(xb + i) = r;
    }
  } else if (blk < 3248) {
    // transposes: fp32[R][C] -> bf16[Rpad][R], zero rows C..Rpad-1
    const float* in; unsigned short* out; int R, C, ldin, ldout, Rpad, bx, by;
    if (blk < 3200) {
      const int idx = blk - 2048;
      in = W_qkv; out = WqkvT; R = 768; C = 1536; ldin = 2304; ldout = 768; Rpad = 1536;
      bx = idx % 48; by = idx / 48;
    } else {
      const int idx = blk - 3200;
      in = W_gp; out = Wgp64; R = 768; C = 49; ldin = 49; ldout = 768; Rpad = 64;
      bx = idx % 2; by = idx / 2;
    }
    const int tx = tid & 31, ty = tid >> 5;
    const int c0 = bx * 32, r0 = by * 32;
    for (int i = ty; i < 32; i += 8) {
      const int r = r0 + i, c = c0 + tx;
      if (r < R && c < C) tsh[i][tx] = f2b(in[(long long)r * ldin + c]);
    }
    __syncthreads();
    for (int i = ty; i < 32; i += 8) {
      const int r = c0 + i, c = r0 + tx;
      if (r < Rpad && c < R) {
        unsigned short v = 0;
        if (r < C) v = tsh[tx][i];
        out[(long long)r * ldout + c] = v;
      }
    }
  } else if (blk < 3392) {
    // Wcomb via MFMA, fp32 sources.
    // A-frag (WprojT[n][d] = W_proj[d][n]): strided gather along d.
    // B-frag (WvB[k][d] = W_qkv[k][1536+d]): CONTIGUOUS along d (fixed).
    const int idx  = blk - 3248;
    const int lane = tid & 63;
    const int wave = tid >> 6;
    const int l15  = lane & 15;
    const int q    = lane >> 4;
    const int q8   = q * 8;
    const int cols0 = (idx % 12) * 64;
    const int rows0 = ((idx / 12) * 4 + wave) * 16;

    floatx4 acc[4];
#pragma unroll
    for (int j = 0; j < 4; ++j) acc[j] = floatx4{0.f, 0.f, 0.f, 0.f};

    for (int kt = 0; kt < 768; kt += 32) {
      short8 af;
#pragma unroll
      for (int u = 0; u < 8; ++u)
        af[u] = (short)f2b(W_proj[(long long)(kt + q8 + u) * 768 + rows0 + l15]);
      short8 bf[4];
#pragma unroll
      for (int j = 0; j < 4; ++j) {
        const float* brow = W_qkv + (long long)(cols0 + j * 16 + l15) * 2304 + 1536 + kt + q8;
        const float4 b0 = *(const float4*)brow;
        const float4 b1 = *(const float4*)(brow + 4);
        bf[j][0] = (short)f2b(b0.x); bf[j][1] = (short)f2b(b0.y);
        bf[j][2] = (short)f2b(b0.z); bf[j][3] = (short)f2b(b0.w);
        bf[j][4] = (short)f2b(b1.x); bf[j][5] = (short)f2b(b1.y);
        bf[j][6] = (short)f2b(b1.z); bf[j][7] = (short)f2b(b1.w);
      }
#pragma unroll
      for (int j = 0; j < 4; ++j)
        acc[j] = __builtin_amdgcn_mfma_f32_16x16x32_bf16(bf[j], af, acc[j], 0, 0, 0);
    }
    unsigned short* out = Wcomb + (long long)(rows0 + l15) * 768 + cols0;
#pragma unroll
    for (int j = 0; j < 4; ++j)
      *(short4v*)&out[j * 16 + q * 4] = pack4(acc[j][0], acc[j][1], acc[j][2], acc[j][3]);
  } else {
    // bias2, one wave per output j (fp32 column gather + shuffle reduce)
    const int lane = tid & 63;
    const int wave = tid >> 6;
    const int j = (blk - 3392) * 4 + wave;
    float s = 0.0f;
#pragma unroll
    for (int tt = 0; tt < 12; ++tt) {
      const int d = tt * 64 + lane;
      s += W_proj[(long long)d * 768 + j] * b_qkv[1536 + d];
    }
#pragma unroll
    for (int m = 1; m < 64; m <<= 1) s += __shfl_xor(s, m, 64);
    if (lane == 0) bias2[j] = b_proj[j] + s;
  }
}

extern "C" void kernel_launch(void* const* d_in, const int* in_sizes, int n_in,
                              void* d_out, int out_size, void* d_ws, size_t ws_size,
                              hipStream_t stream)
{
  const float* x      = (const float*)d_in[0];
  const float* W_qkv  = (const float*)d_in[1];
  const float* b_qkv  = (const float*)d_in[2];
  const float* W_proj = (const float*)d_in[3];
  const float* b_proj = (const float*)d_in[4];
  const float* W_gp   = (const float*)d_in[5];
  const float* alpha  = (const float*)d_in[6];

  char* p = (char*)d_ws;
  auto alloc = [&](size_t bytes) { char* r = p; p += (bytes + 255) & ~255ULL; return r; };
  unsigned short* qk     = (unsigned short*)alloc(16384ULL * 1536 * 2);
  unsigned short* xb     = (unsigned short*)alloc(16384ULL * 768 * 2);
  unsigned short* WqkvT  = (unsigned short*)alloc(1536ULL * 768 * 2);
  unsigned short* Wcomb  = (unsigned short*)alloc(768ULL * 768 * 2);
  unsigned short* Wgp64  = (unsigned short*)alloc(64ULL * 768 * 2);
  unsigned short* gwbuf  = (unsigned short*)alloc(16384ULL * 64 * 2);
  float*          Lbuf   = (float*)alloc(16384ULL * 4);
  float*          bias2  = (float*)alloc(768ULL * 4);
  unsigned short* wmat   = (unsigned short*)alloc(16ULL * 1024 * 1024 * 2);
  unsigned short* vpT    = (unsigned short*)alloc(16ULL * 768 * 1024 * 2);

  const dim3 blk256(256);

  // 1) all input prep in one launch
  prep<<<dim3(3584), blk256, 0, stream>>>(x, W_qkv, b_qkv, W_proj, b_proj, W_gp,
                                          xb, WqkvT, Wgp64, Wcomb, bias2);

  // 2) qk GEMM || vpT GEMM (independent; vpT fills qk's scheduling tail)
  fused_mid<<<dim3(144, 1, 16), blk256, 0, stream>>>(xb, WqkvT, Wcomb, qk, vpT, b_qkv);

  // 3) gw = softmax(q @ W_gp) (also zero-inits L)
  gw_mfma<<<dim3(256), blk256, 0, stream>>>(qk, Wgp64, gwbuf, Lbuf);

  // 4) weights (unnormalized) + L
  score_weights<<<dim3(8, 8, 16), blk256, 0, stream>>>(qk, gwbuf, wmat, Lbuf, alpha);

  // 5) out = (1/L) * wmat @ vpT^T + bias2
  gemm_final<<<dim3(6, 8, 16), blk256, 0, stream>>>(wmat, vpT, (float*)d_out, Lbuf, bias2);
}

// Round 13
// 358.945 us; speedup vs baseline: 1.1103x; 1.1103x over previous
//
#include <hip/hip_runtime.h>
#include <stdint.h>

typedef __attribute__((ext_vector_type(8))) short short8;
typedef __attribute__((ext_vector_type(4))) short short4v;
typedef __attribute__((ext_vector_type(4))) float floatx4;
typedef _Float16 half2v __attribute__((ext_vector_type(2)));

__device__ __forceinline__ float b2f(unsigned short u) {
  union { unsigned int i; float f; } v; v.i = ((unsigned int)u) << 16; return v.f;
}
__device__ __forceinline__ unsigned short f2b(float f) {
  union { float f; unsigned int i; } v; v.f = f;
  unsigned int i = v.i;
  return (unsigned short)((i + 0x7FFFu + ((i >> 16) & 1u)) >> 16);
}
__device__ __forceinline__ short4v pack4(float a, float b, float c, float d) {
  short4v r;
  r[0] = (short)f2b(a); r[1] = (short)f2b(b); r[2] = (short)f2b(c); r[3] = (short)f2b(d);
  return r;
}

// global -> LDS 16B per lane. lds_base wave-uniform; HW adds lane*16B.
__device__ __forceinline__ void stage16(const unsigned short* g, unsigned short* lds_base) {
  __builtin_amdgcn_global_load_lds((__attribute__((address_space(1))) const unsigned int*)g,
                                   (__attribute__((address_space(3))) unsigned int*)lds_base,
                                   16, 0, 0);
}

// ---------------------------------------------------------------------------
// r0/r7/r9-verified 128x128 BK=32 GEMM core (device fn; LDS passed in).
// C[m0+..][n0+..] = sum_k A[row][k]*B[col][k]; optional 1/rd row-scale, bias.
// ---------------------------------------------------------------------------
__device__ __forceinline__ void gemm128_core(
    unsigned short* As, unsigned short* Bs,
    const unsigned short* __restrict__ A, const unsigned short* __restrict__ B,
    unsigned short* __restrict__ Cb, float* __restrict__ Cf,
    const float* __restrict__ rd, const float* __restrict__ bias,
    int K, int lda, int ldb, int ldc, int m0, int n0)
{
  const int tid  = threadIdx.x;
  const int lane = tid & 63;
  const int wave = tid >> 6;
  const int wr = wave >> 1, wc = wave & 1;

  floatx4 acc[4][4];
#pragma unroll
  for (int i = 0; i < 4; ++i)
#pragma unroll
    for (int j = 0; j < 4; ++j) acc[i][j] = floatx4{0.f, 0.f, 0.f, 0.f};

  const int t    = (lane & 7) ^ (lane >> 3);
  const int srow = 2 * (lane >> 3) + (t >> 2);
  const int scol = (t & 3) * 8;
  const unsigned short* ga0 = A + (long long)(m0 + wave * 32 + srow) * lda + scol;
  const unsigned short* ga1 = ga0 + 16LL * lda;
  const unsigned short* gb0 = B + (long long)(n0 + wave * 32 + srow) * ldb + scol;
  const unsigned short* gb1 = gb0 + 16LL * ldb;
  unsigned short* lA0 = As + wave * 1024;
  unsigned short* lA1 = lA0 + 512;
  unsigned short* lB0 = Bs + wave * 1024;
  unsigned short* lB1 = lB0 + 512;

  const int l15  = lane & 15;
  const int q    = lane >> 4;
  const int rofs = (l15 >> 1) * 64 + (((q + 4 * (l15 & 1)) ^ (l15 >> 1)) * 8);

  for (int kt = 0; kt < K; kt += 32) {
    __syncthreads();
    stage16(ga0 + kt, lA0);
    stage16(ga1 + kt, lA1);
    stage16(gb0 + kt, lB0);
    stage16(gb1 + kt, lB1);
    __syncthreads();
    short8 af[4], bfv[4];
#pragma unroll
    for (int i = 0; i < 4; ++i) af[i]  = *(const short8*)&As[(wr * 32 + i * 8) * 64 + rofs];
#pragma unroll
    for (int j = 0; j < 4; ++j) bfv[j] = *(const short8*)&Bs[(wc * 32 + j * 8) * 64 + rofs];
#pragma unroll
    for (int i = 0; i < 4; ++i)
#pragma unroll
      for (int j = 0; j < 4; ++j)
        acc[i][j] = __builtin_amdgcn_mfma_f32_16x16x32_bf16(bfv[j], af[i], acc[i][j], 0, 0, 0);
  }

#pragma unroll
  for (int i = 0; i < 4; ++i) {
    const int row = m0 + wr * 64 + i * 16 + l15;
    const float rcp = rd ? __builtin_amdgcn_rcpf(rd[row]) : 1.0f;
#pragma unroll
    for (int j = 0; j < 4; ++j) {
      const int colb = n0 + wc * 64 + j * 16 + q * 4;
      floatx4 v = acc[i][j];
      if (rd) { v[0] *= rcp; v[1] *= rcp; v[2] *= rcp; v[3] *= rcp; }
      if (bias) {
        const float4 bi = *(const float4*)&bias[colb];
        v[0] += bi.x; v[1] += bi.y; v[2] += bi.z; v[3] += bi.w;
      }
      if (Cb) *(short4v*)&Cb[(long long)row * ldc + colb] = pack4(v[0], v[1], v[2], v[3]);
      else    *(floatx4*)&Cf[(long long)row * ldc + colb] = v;
    }
  }
}

// ---------------------------------------------------------------------------
// fused_mid: qk GEMM (x=0..95 per z) || vpT GEMM (x=96..143 per z).
// Independent outputs; vpT's 768 blocks fill qk's scheduling tail.
// (r11/r12-verified)
// ---------------------------------------------------------------------------
__global__ __launch_bounds__(256, 4) void fused_mid(
    const unsigned short* __restrict__ xb, const unsigned short* __restrict__ WqkvT,
    const unsigned short* __restrict__ Wcomb,
    unsigned short* __restrict__ qk, unsigned short* __restrict__ vpT,
    const float* __restrict__ b_qkv)
{
  __shared__ unsigned short As[128 * 32];
  __shared__ unsigned short Bs[128 * 32];
  const int x  = blockIdx.x;
  const int bz = blockIdx.z;
  if (x < 96) {
    // qk = x @ Wqkv[:, :1536] + b_qkv : m0 encodes batch rows (bz*1024)
    const int m0 = (bz * 8 + (x & 7)) * 128;
    const int n0 = (x >> 3) * 128;
    gemm128_core(As, Bs, xb, WqkvT, qk, (float*)0, (const float*)0, b_qkv,
                 768, 768, 768, 1536, m0, n0);
  } else {
    // vpT[b][j][m] = sum_k Wcomb[j][k] * x[b][m][k]
    const int a  = x - 96;
    const int m0 = (a >> 3) * 128;          // Wcomb rows (768)
    const int n0 = (a & 7) * 128;           // x rows (1024)
    gemm128_core(As, Bs, Wcomb, xb + (long long)bz * 1024 * 768,
                 vpT + (long long)bz * 768 * 1024, (float*)0,
                 (const float*)0, (const float*)0,
                 768, 768, 768, 1024, m0, n0);
  }
}

// final: out[m][j] = (1/L[m]) * sum_n wmat[m][n] * vpT[j][n] + bias2[j]
__global__ __launch_bounds__(256, 4) void gemm_final(
    const unsigned short* __restrict__ wmat, const unsigned short* __restrict__ vpT,
    float* __restrict__ out, const float* __restrict__ L, const float* __restrict__ bias2)
{
  __shared__ unsigned short As[128 * 32];
  __shared__ unsigned short Bs[128 * 32];
  const int bz = blockIdx.z;
  gemm128_core(As, Bs, wmat + (long long)bz * 1024 * 1024, vpT + (long long)bz * 768 * 1024,
               (unsigned short*)0, out + (long long)bz * 1024 * 768,
               L + bz * 1024, bias2,
               1024, 1024, 1024, 768, blockIdx.y * 128, blockIdx.x * 128);
}

// ---------------------------------------------------------------------------
// Fused scores + group + exp (verified r9: rect XCD swizzle).
// ---------------------------------------------------------------------------
__global__ __launch_bounds__(256) void score_weights(
    const unsigned short* __restrict__ qkv, const unsigned short* __restrict__ gw,
    unsigned short* __restrict__ Wout, float* __restrict__ L,
    const float* __restrict__ alpha)
{
  const int tid  = threadIdx.x;
  const int lane = tid & 63;
  const int wave = tid >> 6;
  const int wr = wave >> 1, wc = wave & 1;
  const int bx = blockIdx.x;             // == xcd
  const int by = blockIdx.y;
  const int m0 = ((bx >> 1) * 2 + (by >> 2)) * 128;
  const int n0 = ((bx & 1) * 4 + (by & 3)) * 128;
  const int b  = blockIdx.z;

  const int l15 = lane & 15;
  const int q   = lane >> 4;
  const int q8  = q * 8;

  const unsigned short* gq = gw + ((long long)(b * 1024 + m0 + wr * 64)) * 64;
  const unsigned short* gk = gw + ((long long)(b * 1024 + n0 + wc * 64)) * 64;
  floatx4 gacc[4][4];
#pragma unroll
  for (int i = 0; i < 4; ++i)
#pragma unroll
    for (int j = 0; j < 4; ++j) gacc[i][j] = floatx4{0.f, 0.f, 0.f, 0.f};
#pragma unroll
  for (int ks = 0; ks < 2; ++ks) {
    short8 af[4], bfv[4];
#pragma unroll
    for (int i = 0; i < 4; ++i) af[i]  = *(const short8*)&gq[(long long)(i * 16 + l15) * 64 + ks * 32 + q8];
#pragma unroll
    for (int j = 0; j < 4; ++j) bfv[j] = *(const short8*)&gk[(long long)(j * 16 + l15) * 64 + ks * 32 + q8];
#pragma unroll
    for (int i = 0; i < 4; ++i)
#pragma unroll
      for (int j = 0; j < 4; ++j)
        gacc[i][j] = __builtin_amdgcn_mfma_f32_16x16x32_bf16(bfv[j], af[i], gacc[i][j], 0, 0, 0);
  }
  const float aa    = 1.0f / (1.0f + __expf(-alpha[0]));
  const float onema = 1.0f - aa;
  half2v gfp[4][4][2];
#pragma unroll
  for (int i = 0; i < 4; ++i)
#pragma unroll
    for (int j = 0; j < 4; ++j) {
      gfp[i][j][0] = half2v{(_Float16)(aa + onema * gacc[i][j][0]),
                            (_Float16)(aa + onema * gacc[i][j][1])};
      gfp[i][j][1] = half2v{(_Float16)(aa + onema * gacc[i][j][2]),
                            (_Float16)(aa + onema * gacc[i][j][3])};
    }

  const unsigned short* Aq = qkv + ((long long)(b * 1024 + m0)) * 1536;        // q cols 0..767
  const unsigned short* Bk = qkv + ((long long)(b * 1024 + n0)) * 1536 + 768;  // k cols 768..1535

  __shared__ unsigned short As[128 * 32];
  __shared__ unsigned short Bs[128 * 32];

  floatx4 sacc[4][4];
#pragma unroll
  for (int i = 0; i < 4; ++i)
#pragma unroll
    for (int j = 0; j < 4; ++j) sacc[i][j] = floatx4{0.f, 0.f, 0.f, 0.f};

  const int t    = (lane & 7) ^ (lane >> 3);
  const int srow = 2 * (lane >> 3) + (t >> 2);
  const int scol = (t & 3) * 8;
  const unsigned short* ga0 = Aq + (long long)(wave * 32 + srow) * 1536 + scol;
  const unsigned short* ga1 = ga0 + 16LL * 1536;
  const unsigned short* gb0 = Bk + (long long)(wave * 32 + srow) * 1536 + scol;
  const unsigned short* gb1 = gb0 + 16LL * 1536;
  unsigned short* lA0 = As + wave * 1024;
  unsigned short* lA1 = lA0 + 512;
  unsigned short* lB0 = Bs + wave * 1024;
  unsigned short* lB1 = lB0 + 512;

  const int rofs = (l15 >> 1) * 64 + (((q + 4 * (l15 & 1)) ^ (l15 >> 1)) * 8);

  for (int kt = 0; kt < 768; kt += 32) {
    __syncthreads();
    stage16(ga0 + kt, lA0);
    stage16(ga1 + kt, lA1);
    stage16(gb0 + kt, lB0);
    stage16(gb1 + kt, lB1);
    __syncthreads();
    short8 af[4], bfv[4];
#pragma unroll
    for (int i = 0; i < 4; ++i) af[i]  = *(const short8*)&As[(wr * 32 + i * 8) * 64 + rofs];
#pragma unroll
    for (int j = 0; j < 4; ++j) bfv[j] = *(const short8*)&Bs[(wc * 32 + j * 8) * 64 + rofs];
#pragma unroll
    for (int i = 0; i < 4; ++i)
#pragma unroll
      for (int j = 0; j < 4; ++j)
        sacc[i][j] = __builtin_amdgcn_mfma_f32_16x16x32_bf16(bfv[j], af[i], sacc[i][j], 0, 0, 0);
  }

  const float scale = 0.03608439182435161f;
  unsigned short* Wb = Wout + ((long long)b << 20);

#pragma unroll
  for (int i = 0; i < 4; ++i) {
    const int row = m0 + wr * 64 + i * 16 + l15;
    float ls = 0.0f;
#pragma unroll
    for (int j = 0; j < 4; ++j) {
      const int colb = n0 + wc * 64 + j * 16 + q * 4;
      float e0 = __expf(sacc[i][j][0] * scale);
      float e1 = __expf(sacc[i][j][1] * scale);
      float e2 = __expf(sacc[i][j][2] * scale);
      float e3 = __expf(sacc[i][j][3] * scale);
      ls += (e0 + e1) + (e2 + e3);
      *(short4v*)&Wb[(long long)row * 1024 + colb] =
        pack4(e0 * (float)gfp[i][j][0][0], e1 * (float)gfp[i][j][0][1],
              e2 * (float)gfp[i][j][1][0], e3 * (float)gfp[i][j][1][1]);
    }
    ls += __shfl_xor(ls, 16, 64);
    ls += __shfl_xor(ls, 32, 64);
    if (lane < 16) atomicAdd(&L[b * 1024 + row], ls);
  }
}

// ---------------------------------------------------------------------------
// MFMA-based gw (verified r5-r12; also zero-inits L).
// ---------------------------------------------------------------------------
__global__ __launch_bounds__(256) void gw_mfma(
    const unsigned short* __restrict__ qkv, const unsigned short* __restrict__ Wgp64,
    unsigned short* __restrict__ gw, float* __restrict__ L)
{
  const int lane = threadIdx.x & 63;
  const int wave = threadIdx.x >> 6;
  const int l15  = lane & 15;
  const int q    = lane >> 4;
  const int q8   = q * 8;
  const long long row0 = (long long)blockIdx.x * 64 + wave * 16;
  const unsigned short* A = qkv + row0 * 1536;

  if (q == 0) L[row0 + l15] = 0.0f;

  floatx4 acc[4];
#pragma unroll
  for (int j = 0; j < 4; ++j) acc[j] = floatx4{0.f, 0.f, 0.f, 0.f};

  for (int kt = 0; kt < 768; kt += 32) {
    short8 af = *(const short8*)&A[(long long)l15 * 1536 + kt + q8];
    short8 bf[4];
#pragma unroll
    for (int j = 0; j < 4; ++j)
      bf[j] = *(const short8*)&Wgp64[(j * 16 + l15) * 768 + kt + q8];
#pragma unroll
    for (int j = 0; j < 4; ++j)
      acc[j] = __builtin_amdgcn_mfma_f32_16x16x32_bf16(bf[j], af, acc[j], 0, 0, 0);
  }

  float mx = -1e30f;
#pragma unroll
  for (int j = 0; j < 4; ++j)
#pragma unroll
    for (int e = 0; e < 4; ++e) {
      const int col = j * 16 + q * 4 + e;
      if (col < 49) mx = fmaxf(mx, acc[j][e]);
    }
  mx = fmaxf(mx, __shfl_xor(mx, 16, 64));
  mx = fmaxf(mx, __shfl_xor(mx, 32, 64));

  float ev[4][4];
  float s = 0.0f;
#pragma unroll
  for (int j = 0; j < 4; ++j)
#pragma unroll
    for (int e = 0; e < 4; ++e) {
      const int col = j * 16 + q * 4 + e;
      const float x = (col < 49) ? __expf(acc[j][e] - mx) : 0.0f;
      ev[j][e] = x;
      s += x;
    }
  s += __shfl_xor(s, 16, 64);
  s += __shfl_xor(s, 32, 64);
  const float inv = 1.0f / s;

  unsigned short* out = gw + (row0 + l15) * 64;
#pragma unroll
  for (int j = 0; j < 4; ++j)
    *(short4v*)&out[j * 16 + q * 4] =
      pack4(ev[j][0] * inv, ev[j][1] * inv, ev[j][2] * inv, ev[j][3] * inv);
}

// ---------------------------------------------------------------------------
// 768x768x768 parallel GEMM for Wcomb (verified r7-r9: bf16 row-major
// inputs, coalesced). Wcomb[n][k] = sum_d WprojT[n][d] * WvB[k][d].
// ---------------------------------------------------------------------------
__global__ __launch_bounds__(256) void small_gemm_nt(
    const unsigned short* __restrict__ A, const unsigned short* __restrict__ B,
    unsigned short* __restrict__ C)
{
  const int lane = threadIdx.x & 63;
  const int wave = threadIdx.x >> 6;
  const int l15  = lane & 15;
  const int q    = lane >> 4;
  const int q8   = q * 8;
  const int rows0 = (blockIdx.y * 4 + wave) * 16;
  const int cols0 = blockIdx.x * 64;

  floatx4 acc[4];
#pragma unroll
  for (int j = 0; j < 4; ++j) acc[j] = floatx4{0.f, 0.f, 0.f, 0.f};

  for (int kt = 0; kt < 768; kt += 32) {
    short8 af = *(const short8*)&A[(rows0 + l15) * 768 + kt + q8];
    short8 bf[4];
#pragma unroll
    for (int j = 0; j < 4; ++j)
      bf[j] = *(const short8*)&B[(cols0 + j * 16 + l15) * 768 + kt + q8];
#pragma unroll
    for (int j = 0; j < 4; ++j)
      acc[j] = __builtin_amdgcn_mfma_f32_16x16x32_bf16(bf[j], af, acc[j], 0, 0, 0);
  }

  unsigned short* out = C + (rows0 + l15) * 768 + cols0;
#pragma unroll
  for (int j = 0; j < 4; ++j)
    *(short4v*)&out[j * 16 + q * 4] = pack4(acc[j][0], acc[j][1], acc[j][2], acc[j][3]);
}

// grid-stride fp32 -> bf16, 16B stores (n must be a multiple of 8). (r9)
__global__ void convert_f2b(const float* __restrict__ in, unsigned short* __restrict__ out, long long n)
{
  const long long stride = (long long)gridDim.x * blockDim.x * 8;
  for (long long i = ((long long)blockIdx.x * blockDim.x + threadIdx.x) * 8; i < n; i += stride) {
    const float4 a = *(const float4*)(in + i);
    const float4 b = *(const float4*)(in + i + 4);
    short8 r;
    r[0] = (short)f2b(a.x); r[1] = (short)f2b(a.y); r[2] = (short)f2b(a.z); r[3] = (short)f2b(a.w);
    r[4] = (short)f2b(b.x); r[5] = (short)f2b(b.y); r[6] = (short)f2b(b.z); r[7] = (short)f2b(b.w);
    *(short8*)(out + i) = r;
  }
}

// transpose fp32[R][C] -> bf16[Rpad][R]; rows C..Rpad-1 zeroed. (r9)
__global__ void transpose_f2b(const float* __restrict__ in, unsigned short* __restrict__ out,
                              int R, int C, int ldin, int ldout, int Rpad)
{
  __shared__ unsigned short t[32][33];
  const int c0 = blockIdx.x * 32, r0 = blockIdx.y * 32;
  for (int i = threadIdx.y; i < 32; i += 8) {
    const int r = r0 + i, c = c0 + threadIdx.x;
    if (r < R && c < C) t[i][threadIdx.x] = f2b(in[(long long)r * ldin + c]);
  }
  __syncthreads();
  for (int i = threadIdx.y; i < 32; i += 8) {
    const int r = c0 + i, c = r0 + threadIdx.x;
    if (r < Rpad && c < R) {
      unsigned short v = 0;
      if (r < C) v = t[threadIdx.x][i];
      out[(long long)r * ldout + c] = v;
    }
  }
}

// WvB[768][768] bf16 = W_qkv[:, 1536:2304] (row-major slice convert) (r9)
__global__ void slice_f2b(const float* __restrict__ in, unsigned short* __restrict__ out)
{
  const long long idx = (long long)blockIdx.x * 256 + threadIdx.x;
  const int r = (int)(idx / 768), c = (int)(idx - (long long)r * 768);
  out[idx] = f2b(in[(long long)r * 2304 + 1536 + c]);
}

// bias2[j] = b_proj[j] + sum_d WprojT[j][d] * b_qkv[1536+d]
// one wave per j, coalesced bf16 row reads + shuffle reduce. (r9)
__global__ __launch_bounds__(256) void bias2_kernel(
    const unsigned short* __restrict__ WprojT, const float* __restrict__ b_qkv,
    const float* __restrict__ b_proj, float* __restrict__ bias2)
{
  const int lane = threadIdx.x & 63;
  const int wave = threadIdx.x >> 6;
  const int j = blockIdx.x * 4 + wave;
  float s = 0.0f;
#pragma unroll
  for (int tt = 0; tt < 12; ++tt) {
    const int d = tt * 64 + lane;
    s += b2f(WprojT[j * 768 + d]) * b_qkv[1536 + d];
  }
#pragma unroll
  for (int m = 1; m < 64; m <<= 1) s += __shfl_xor(s, m, 64);
  if (lane == 0) bias2[j] = b_proj[j] + s;
}

extern "C" void kernel_launch(void* const* d_in, const int* in_sizes, int n_in,
                              void* d_out, int out_size, void* d_ws, size_t ws_size,
                              hipStream_t stream)
{
  const float* x      = (const float*)d_in[0];
  const float* W_qkv  = (const float*)d_in[1];
  const float* b_qkv  = (const float*)d_in[2];
  const float* W_proj = (const float*)d_in[3];
  const float* b_proj = (const float*)d_in[4];
  const float* W_gp   = (const float*)d_in[5];
  const float* alpha  = (const float*)d_in[6];

  char* p = (char*)d_ws;
  auto alloc = [&](size_t bytes) { char* r = p; p += (bytes + 255) & ~255ULL; return r; };
  unsigned short* qk     = (unsigned short*)alloc(16384ULL * 1536 * 2);
  unsigned short* xb     = (unsigned short*)alloc(16384ULL * 768 * 2);
  unsigned short* WqkvT  = (unsigned short*)alloc(1536ULL * 768 * 2);
  unsigned short* WprojT = (unsigned short*)alloc(768ULL * 768 * 2);
  unsigned short* WvB    = (unsigned short*)alloc(768ULL * 768 * 2);
  unsigned short* Wcomb  = (unsigned short*)alloc(768ULL * 768 * 2);
  unsigned short* Wgp64  = (unsigned short*)alloc(64ULL * 768 * 2);
  unsigned short* gwbuf  = (unsigned short*)alloc(16384ULL * 64 * 2);
  float*          Lbuf   = (float*)alloc(16384ULL * 4);
  float*          bias2  = (float*)alloc(768ULL * 4);
  unsigned short* wmat   = (unsigned short*)alloc(16ULL * 1024 * 1024 * 2);
  unsigned short* vpT    = (unsigned short*)alloc(16ULL * 768 * 1024 * 2);

  const dim3 blk256(256);
  const dim3 tb(32, 8);

  // prep: the r9-verified separate kernels (merged prep was a 113 us
  // straggler pathology in r12 — reverted for speed AND observability)
  convert_f2b<<<dim3(2048), blk256, 0, stream>>>(x, xb, 16384LL * 768);
  transpose_f2b<<<dim3(48, 24), tb, 0, stream>>>(W_qkv, WqkvT, 768, 1536, 2304, 768, 1536);
  transpose_f2b<<<dim3(24, 24), tb, 0, stream>>>(W_proj, WprojT, 768, 768, 768, 768, 768);
  transpose_f2b<<<dim3(2, 24), tb, 0, stream>>>(W_gp, Wgp64, 768, 49, 49, 768, 64);
  slice_f2b<<<dim3(2304), blk256, 0, stream>>>(W_qkv, WvB);
  small_gemm_nt<<<dim3(12, 12), blk256, 0, stream>>>(WprojT, WvB, Wcomb);
  bias2_kernel<<<dim3(192), blk256, 0, stream>>>(WprojT, b_qkv, b_proj, bias2);

  // qk GEMM || vpT GEMM (independent; vpT fills qk's scheduling tail)
  fused_mid<<<dim3(144, 1, 16), blk256, 0, stream>>>(xb, WqkvT, Wcomb, qk, vpT, b_qkv);

  // gw = softmax(q @ W_gp) (also zero-inits L)
  gw_mfma<<<dim3(256), blk256, 0, stream>>>(qk, Wgp64, gwbuf, Lbuf);

  // weights (unnormalized) + L
  score_weights<<<dim3(8, 8, 16), blk256, 0, stream>>>(qk, gwbuf, wmat, Lbuf, alpha);

  // out = (1/L) * wmat @ vpT^T + bias2
  gemm_final<<<dim3(6, 8, 16), blk256, 0, stream>>>(wmat, vpT, (float*)d_out, Lbuf, bias2);
}